// Round 1
// baseline (638.605 us; speedup 1.0000x reference)
//
#include <hip/hip_runtime.h>
#include <math.h>

#define B_   8
#define L_   4
#define P_   1024
#define C_   256
#define NH_  8
#define NS_  4
#define HD_  32

// ---------------------------------------------------------------------------
// Transpose (B, C, S) -> (B, S, C) per level, S = H*W.  LDS-tiled, both sides
// coalesced. grid = (S/32, C_/32, B_), block = (32, 8).
// ---------------------------------------------------------------------------
__global__ void transpose_feat_kernel(const float* __restrict__ src,
                                      float* __restrict__ dst, int S) {
  __shared__ float tile[32][33];
  int b  = blockIdx.z;
  int s0 = blockIdx.x * 32;
  int c0 = blockIdx.y * 32;
  const float* sb = src + (size_t)b * C_ * S;
  float*       db = dst + (size_t)b * S * C_;
  int lx = threadIdx.x;  // 0..31
  for (int r = threadIdx.y; r < 32; r += 8)
    tile[r][lx] = sb[(size_t)(c0 + r) * S + (s0 + lx)];
  __syncthreads();
  for (int r = threadIdx.y; r < 32; r += 8)
    db[(size_t)(s0 + r) * C_ + (c0 + lx)] = tile[lx][r];
}

// ---------------------------------------------------------------------------
// Main kernel: one block per point (b,l,p), 256 threads (thread = channel).
// ---------------------------------------------------------------------------
__global__ __launch_bounds__(256) void deform_main(
    const float* __restrict__ x,        // (B,L,P,C)
    const float* __restrict__ ref,      // (B,L,P,2)
    const float* __restrict__ ft,       // transposed feats, all levels concat
    const float* __restrict__ w_attn,   // (C, 32)
    const float* __restrict__ b_attn,   // (32)
    const float* __restrict__ w_off,    // (C, 64)
    const float* __restrict__ b_off,    // (64)
    const float* __restrict__ embed_w,  // (L, C, HD)
    const float* __restrict__ embed_b,  // (L, HD)
    float* __restrict__ out)            // (B,L,P,C)
{
  const int t   = threadIdx.x;
  const int blk = blockIdx.x;            // = ((b*L + l)*P + p)
  const int l   = (blk >> 10) & 3;
  const int b   = blk >> 12;

  __shared__ float xs[C_];
  __shared__ float wts[NH_ * NS_];       // logits, then softmax weights
  __shared__ float posx[NH_ * NS_];
  __shared__ float posy[NH_ * NS_];
  __shared__ float cmb[NH_][C_];         // per-head combined sample vectors

  const size_t xoff = (size_t)blk * C_;
  xs[t] = x[xoff + t];
  __syncthreads();

  const int Wl = 64 >> l;                // H == W per level
  const int Hl = Wl;
  const size_t lvl_off[4] = {0u, 8388608u, 10485760u, 11010048u};
  const float* fl = ft + lvl_off[l] + (size_t)b * Hl * Wl * C_;

  // ---- 96 dot products: 32 attn logits + 64 offset logits ----
  if (t < 96) {
    if (t < 32) {
      float acc = b_attn[t];
      #pragma unroll 8
      for (int c = 0; c < C_; ++c) acc += xs[c] * w_attn[c * 32 + t];
      wts[t] = acc;                      // raw logit
    } else {
      const int j = t - 32;              // 0..63 : (sample j>>1, axis j&1)
      float acc = b_off[j];
      #pragma unroll 8
      for (int c = 0; c < C_; ++c) acc += xs[c] * w_off[c * 64 + j];
      const float v = tanhf(acc) + ref[(size_t)blk * 2 + (j & 1)];
      if ((j & 1) == 0) posx[j >> 1] = v;
      else              posy[j >> 1] = v;
    }
  }
  __syncthreads();

  // ---- softmax over NS per head (threads 0..7); in-place is safe ----
  if (t < NH_) {
    float m = -1e30f;
    #pragma unroll
    for (int s = 0; s < NS_; ++s) m = fmaxf(m, wts[t * NS_ + s]);
    float e[NS_], sum = 0.f;
    #pragma unroll
    for (int s = 0; s < NS_; ++s) { e[s] = expf(wts[t * NS_ + s] - m); sum += e[s]; }
    const float inv = 1.f / sum;
    #pragma unroll
    for (int s = 0; s < NS_; ++s) wts[t * NS_ + s] = e[s] * inv;
  }
  __syncthreads();

  // ---- bilinear sampling, weighted-combined per head ----
  const float sx = 0.5f * (float)(Wl - 1);
  const float sy = 0.5f * (float)(Hl - 1);
  for (int h = 0; h < NH_; ++h) {
    float acc = 0.f;
    #pragma unroll
    for (int s = 0; s < NS_; ++s) {
      const int j = h * NS_ + s;
      const float fx = (posx[j] + 1.f) * sx;
      const float fy = (posy[j] + 1.f) * sy;
      const float x0f = floorf(fx), y0f = floorf(fy);
      const int x0 = (int)x0f, y0 = (int)y0f;
      const int x1 = x0 + 1,   y1 = y0 + 1;
      const float wx1 = fx - x0f, wy1 = fy - y0f;
      const float wx0 = 1.f - wx1, wy0 = 1.f - wy1;
      const bool xv0 = (x0 >= 0) & (x0 < Wl);
      const bool xv1 = (x1 >= 0) & (x1 < Wl);
      const bool yv0 = (y0 >= 0) & (y0 < Hl);
      const bool yv1 = (y1 >= 0) & (y1 < Hl);
      float v00 = 0.f, v01 = 0.f, v10 = 0.f, v11 = 0.f;
      if (yv0 & xv0) v00 = fl[(size_t)(y0 * Wl + x0) * C_ + t];
      if (yv0 & xv1) v01 = fl[(size_t)(y0 * Wl + x1) * C_ + t];
      if (yv1 & xv0) v10 = fl[(size_t)(y1 * Wl + x0) * C_ + t];
      if (yv1 & xv1) v11 = fl[(size_t)(y1 * Wl + x1) * C_ + t];
      const float bil = wy0 * (wx0 * v00 + wx1 * v01)
                      + wy1 * (wx0 * v10 + wx1 * v11);
      acc += wts[j] * bil;
    }
    cmb[h][t] = acc;
  }
  __syncthreads();

  // ---- projection: out channel t = (h = t>>5, d = t&31) ----
  const int h = t >> 5, d = t & 31;
  const float* E = embed_w + ((size_t)l * C_) * HD_ + d;
  float acc = embed_b[l * HD_ + d];
  #pragma unroll 8
  for (int c = 0; c < C_; ++c) acc += cmb[h][c] * E[(size_t)c * HD_];
  out[xoff + t] = acc;
}

// ---------------------------------------------------------------------------
extern "C" void kernel_launch(void* const* d_in, const int* in_sizes, int n_in,
                              void* d_out, int out_size, void* d_ws, size_t ws_size,
                              hipStream_t stream) {
  const float* x      = (const float*)d_in[0];
  const float* ref    = (const float*)d_in[1];
  const float* w_attn = (const float*)d_in[6];
  const float* b_attn = (const float*)d_in[7];
  const float* w_off  = (const float*)d_in[8];
  const float* b_off  = (const float*)d_in[9];
  const float* emb_w  = (const float*)d_in[10];
  const float* emb_b  = (const float*)d_in[11];
  float* ws  = (float*)d_ws;
  float* out = (float*)d_out;

  const size_t offs[4] = {0u, 8388608u, 10485760u, 11010048u};
  const int    Sv[4]   = {4096, 1024, 256, 64};

  for (int lv = 0; lv < 4; ++lv) {
    dim3 grid(Sv[lv] / 32, C_ / 32, B_);
    transpose_feat_kernel<<<grid, dim3(32, 8), 0, stream>>>(
        (const float*)d_in[2 + lv], ws + offs[lv], Sv[lv]);
  }

  deform_main<<<B_ * L_ * P_, 256, 0, stream>>>(
      x, ref, ws, w_attn, b_attn, w_off, b_off, emb_w, emb_b, out);
}

// Round 2
// 537.025 us; speedup vs baseline: 1.1892x; 1.1892x over previous
//
#include <hip/hip_runtime.h>
#include <math.h>

#define B_   8
#define L_   4
#define P_   1024
#define C_   256
#define NH_  8
#define NS_  4
#define HD_  32

// ws layout (floats)
#define FT_F    0u           // transposed feats, 11,141,120 floats
#define SAMP_F  11141120u    // per-sample (w, fx, fy, 0) float4: 32768*32*4 floats

// ---------------------------------------------------------------------------
// Transpose (B, C, S) -> (B, S, C) per level, S = H*W.
// ---------------------------------------------------------------------------
__global__ void transpose_feat_kernel(const float* __restrict__ src,
                                      float* __restrict__ dst, int S) {
  __shared__ float tile[32][33];
  int b  = blockIdx.z;
  int s0 = blockIdx.x * 32;
  int c0 = blockIdx.y * 32;
  const float* sb = src + (size_t)b * C_ * S;
  float*       db = dst + (size_t)b * S * C_;
  int lx = threadIdx.x;
  for (int r = threadIdx.y; r < 32; r += 8)
    tile[r][lx] = sb[(size_t)(c0 + r) * S + (s0 + lx)];
  __syncthreads();
  for (int r = threadIdx.y; r < 32; r += 8)
    db[(size_t)(s0 + r) * C_ + (c0 + lx)] = tile[lx][r];
}

// ---------------------------------------------------------------------------
// K2: batched logits + softmax + tanh + grid mapping. 32 points per block.
// Emits per sample: (w, fx, fy, 0) with fx,fy in grid pixel coords.
// ---------------------------------------------------------------------------
__global__ __launch_bounds__(256) void k2_logits(
    const float* __restrict__ x,       // (32768, 256)
    const float* __restrict__ ref,     // (32768, 2)
    const float* __restrict__ w_attn,  // (256, 32)
    const float* __restrict__ b_attn,
    const float* __restrict__ w_off,   // (256, 64)
    const float* __restrict__ b_off,
    float4* __restrict__ samp4)        // (32768, 32)
{
  __shared__ float smem[32 * 264];     // x tile (padded stride), later logits
  const int t   = threadIdx.x;
  const int blk = blockIdx.x;          // 1024 blocks

  // stage 32 x-rows, padded stride 264 floats (66 float4) to spread banks
  {
    const float4* x4 = (const float4*)x + (size_t)blk * 2048;
    float4* s4 = (float4*)smem;
    #pragma unroll
    for (int q = 0; q < 8; ++q) {
      int e = q * 256 + t;
      s4[(e >> 6) * 66 + (e & 63)] = x4[e];
    }
  }
  __syncthreads();

  // each point handled by 8 threads; each thread: 12 outputs of 96
  const int jg = t & 7;
  const int p  = t >> 3;
  const float* xr = smem + p * 264;
  float acc[12];
  #pragma unroll
  for (int i = 0; i < 12; ++i) {
    const int j = i * 8 + jg;
    float a;
    if (i < 4) {                       // attn logits (i compile-time)
      const float* wp = w_attn + j;
      a = b_attn[j];
      #pragma unroll 4
      for (int c = 0; c < 256; ++c) a += xr[c] * wp[(size_t)c * 32];
    } else {                           // offset logits
      const float* wp = w_off + (j - 32);
      a = b_off[j - 32];
      #pragma unroll 4
      for (int c = 0; c < 256; ++c) a += xr[c] * wp[(size_t)c * 64];
    }
    acc[i] = a;
  }
  __syncthreads();                     // done reading x tile

  float* lg = smem;                    // reuse: logits (32, 96)
  #pragma unroll
  for (int i = 0; i < 12; ++i) lg[p * 96 + i * 8 + jg] = acc[i];
  __syncthreads();

  // 4 (point, sample) slots per thread: softmax weight + tanh offsets
  #pragma unroll
  for (int k = 0; k < 4; ++k) {
    const int slot = k * 256 + t;
    const int pp = slot >> 5, j = slot & 31;
    const int gp = blk * 32 + pp;
    const int l  = (gp >> 10) & 3;
    const int Wl = 64 >> l;
    const float* lgp = lg + pp * 96;
    const int h4 = (j >> 2) * 4;
    const float l0 = lgp[h4], l1 = lgp[h4 + 1], l2 = lgp[h4 + 2], l3 = lgp[h4 + 3];
    const float m = fmaxf(fmaxf(l0, l1), fmaxf(l2, l3));
    const float e0 = expf(l0 - m), e1 = expf(l1 - m), e2 = expf(l2 - m), e3 = expf(l3 - m);
    const float inv = 1.f / (e0 + e1 + e2 + e3);
    const float es[4] = {e0, e1, e2, e3};
    const float wj = es[j & 3] * inv;
    const float ox = tanhf(lgp[32 + 2 * j])     + ref[(size_t)gp * 2];
    const float oy = tanhf(lgp[32 + 2 * j + 1]) + ref[(size_t)gp * 2 + 1];
    const float sc = 0.5f * (float)(Wl - 1);
    samp4[(size_t)gp * 32 + j] = make_float4(wj, (ox + 1.f) * sc, (oy + 1.f) * sc, 0.f);
  }
}

// ---------------------------------------------------------------------------
// K3: per point: tap precompute (32 threads) -> 128 coalesced taps -> proj.
// ---------------------------------------------------------------------------
__global__ __launch_bounds__(256) void k3_main(
    const float* __restrict__ ft,
    const float4* __restrict__ samp4,
    const float* __restrict__ embed_w,  // (L, 256, 32)
    const float* __restrict__ embed_b,  // (L, 32)
    float* __restrict__ out)            // (32768, 256)
{
  const int t  = threadIdx.x;
  const int gp = blockIdx.x;
  const int l  = (gp >> 10) & 3;
  const int b  = gp >> 12;

  __shared__ int4   tofs[NH_ * NS_];
  __shared__ float4 tws[NH_ * NS_];
  __shared__ float  cmb[NH_][C_];

  if (t < 32) {
    const float4 s = samp4[(size_t)gp * 32 + t];
    const int Wl = 64 >> l;
    const int lvl_off[4] = {0, 8388608, 10485760, 11010048};
    const int base = lvl_off[l] + b * Wl * Wl * C_;
    const float fx = s.y, fy = s.z;
    const float x0f = floorf(fx), y0f = floorf(fy);
    const int x0 = (int)x0f, y0 = (int)y0f, x1 = x0 + 1, y1 = y0 + 1;
    const float wx1 = fx - x0f, wy1 = fy - y0f;
    const float wx0 = 1.f - wx1, wy0 = 1.f - wy1;
    const float xv0 = (x0 >= 0 && x0 < Wl) ? 1.f : 0.f;
    const float xv1 = (x1 >= 0 && x1 < Wl) ? 1.f : 0.f;
    const float yv0 = (y0 >= 0 && y0 < Wl) ? 1.f : 0.f;
    const float yv1 = (y1 >= 0 && y1 < Wl) ? 1.f : 0.f;
    const int x0c = min(max(x0, 0), Wl - 1), x1c = min(max(x1, 0), Wl - 1);
    const int y0c = min(max(y0, 0), Wl - 1), y1c = min(max(y1, 0), Wl - 1);
    tofs[t] = make_int4(base + (y0c * Wl + x0c) * C_,
                        base + (y0c * Wl + x1c) * C_,
                        base + (y1c * Wl + x0c) * C_,
                        base + (y1c * Wl + x1c) * C_);
    const float w = s.x;
    tws[t] = make_float4(w * wy0 * wx0 * yv0 * xv0,
                         w * wy0 * wx1 * yv0 * xv1,
                         w * wy1 * wx0 * yv1 * xv0,
                         w * wy1 * wx1 * yv1 * xv1);
  }
  __syncthreads();

  #pragma unroll
  for (int h = 0; h < NH_; ++h) {
    float a = 0.f;
    #pragma unroll
    for (int s = 0; s < NS_; ++s) {
      const int j = h * NS_ + s;
      const int4   o = tofs[j];
      const float4 w = tws[j];
      a += w.x * ft[o.x + t] + w.y * ft[o.y + t]
         + w.z * ft[o.z + t] + w.w * ft[o.w + t];
    }
    cmb[h][t] = a;
  }
  __syncthreads();

  const int h = t >> 5, d = t & 31;
  const float* E = embed_w + (size_t)l * (C_ * HD_) + d;
  const float4* cr4 = (const float4*)cmb[h];
  float a = embed_b[l * HD_ + d];
  #pragma unroll 8
  for (int c4 = 0; c4 < 64; ++c4) {
    const float4 v = cr4[c4];
    const int c = c4 * 4;
    a += v.x * E[(size_t)c * HD_]       + v.y * E[(size_t)(c + 1) * HD_]
       + v.z * E[(size_t)(c + 2) * HD_] + v.w * E[(size_t)(c + 3) * HD_];
  }
  out[(size_t)gp * C_ + t] = a;
}

// ---------------------------------------------------------------------------
extern "C" void kernel_launch(void* const* d_in, const int* in_sizes, int n_in,
                              void* d_out, int out_size, void* d_ws, size_t ws_size,
                              hipStream_t stream) {
  const float* x      = (const float*)d_in[0];
  const float* ref    = (const float*)d_in[1];
  const float* w_attn = (const float*)d_in[6];
  const float* b_attn = (const float*)d_in[7];
  const float* w_off  = (const float*)d_in[8];
  const float* b_off  = (const float*)d_in[9];
  const float* emb_w  = (const float*)d_in[10];
  const float* emb_b  = (const float*)d_in[11];
  float* ws  = (float*)d_ws;
  float* out = (float*)d_out;

  const size_t offs[4] = {0u, 8388608u, 10485760u, 11010048u};
  const int    Sv[4]   = {4096, 1024, 256, 64};

  for (int lv = 0; lv < 4; ++lv) {
    dim3 grid(Sv[lv] / 32, C_ / 32, B_);
    transpose_feat_kernel<<<grid, dim3(32, 8), 0, stream>>>(
        (const float*)d_in[2 + lv], ws + FT_F + offs[lv], Sv[lv]);
  }

  float4* samp4 = (float4*)(ws + SAMP_F);
  k2_logits<<<B_ * L_ * P_ / 32, 256, 0, stream>>>(
      x, ref, w_attn, b_attn, w_off, b_off, samp4);

  k3_main<<<B_ * L_ * P_, 256, 0, stream>>>(
      ws + FT_F, samp4, emb_w, emb_b, out);
}

// Round 3
// 151.635 us; speedup vs baseline: 4.2115x; 3.5416x over previous
//
#include <hip/hip_runtime.h>
#include <math.h>

#define B_   8
#define L_   4
#define P_   1024
#define C_   256
#define NH_  8
#define NS_  4
#define HD_  32

// ws layout (float offsets)
#define G_F     0u          // projected maps (l,b,s,32): 1,392,640 floats
#define SAMP_F  1392640u    // per-sample (w,fx,fy,0) float4: 32768*32*4 floats
#define WU_F    5586944u    // unified W (256,96)
#define BU_F    5611520u    // unified bias (96)

__constant__ const int kGoff[4] = {0, 1048576, 1310720, 1376256};

// ---------------------------------------------------------------------------
// k0: unify [w_attn | w_off] -> Wu (256,96), biases -> bu (96)
// ---------------------------------------------------------------------------
__global__ void k0_unify(const float* __restrict__ wa, const float* __restrict__ ba,
                         const float* __restrict__ wo, const float* __restrict__ bo,
                         float* __restrict__ Wu, float* __restrict__ bu) {
  const int c = blockIdx.x, j = threadIdx.x;
  Wu[c * 96 + j] = (j < 32) ? wa[c * 32 + j] : wo[c * 64 + (j - 32)];
  if (c == 0) bu[j] = (j < 32) ? ba[j] : bo[j - 32];
}

// ---------------------------------------------------------------------------
// gproj: fused transpose+project  g(b,s,:) = feat(b,:,s) @ E_l   (32 outputs)
// grid = (85, B_), block 256.  bx<64:l0 tile, <80:l1, <84:l2, else l3.
// ---------------------------------------------------------------------------
__global__ __launch_bounds__(256) void gproj(
    const float* __restrict__ f0, const float* __restrict__ f1,
    const float* __restrict__ f2, const float* __restrict__ f3,
    const float* __restrict__ embed_w, float* __restrict__ g) {
  __shared__ float eL[C_ * HD_];   // 32 KB
  __shared__ float fl[32][64];     // 8 KB
  const int t = threadIdx.x;
  const int b = blockIdx.y;
  int bx = blockIdx.x, l, tile;
  const float* src;
  if (bx < 64)      { l = 0; tile = bx;      src = f0; }
  else if (bx < 80) { l = 1; tile = bx - 64; src = f1; }
  else if (bx < 84) { l = 2; tile = bx - 80; src = f2; }
  else              { l = 3; tile = 0;       src = f3; }
  const int Wl = 64 >> l, S = Wl * Wl;
  const int s0 = tile * 64;

  const float* E = embed_w + (size_t)l * (C_ * HD_);
  #pragma unroll
  for (int q = 0; q < 32; ++q) eL[q * 256 + t] = E[q * 256 + t];

  const float* sb = src + (size_t)b * C_ * S + s0;
  const int sl = t & 63, dg = t >> 6;
  float acc[8];
  #pragma unroll
  for (int e = 0; e < 8; ++e) acc[e] = 0.f;

  for (int c0 = 0; c0 < 256; c0 += 32) {
    __syncthreads();
    #pragma unroll
    for (int q = 0; q < 8; ++q) {
      const int e = q * 256 + t;
      fl[e >> 6][e & 63] = sb[(size_t)(c0 + (e >> 6)) * S + (e & 63)];
    }
    __syncthreads();
    #pragma unroll 8
    for (int ci = 0; ci < 32; ++ci) {
      const float f = fl[ci][sl];
      const float4* ep = (const float4*)&eL[(c0 + ci) * 32 + dg * 8];
      const float4 e0 = ep[0], e1 = ep[1];
      acc[0] += f * e0.x; acc[1] += f * e0.y; acc[2] += f * e0.z; acc[3] += f * e0.w;
      acc[4] += f * e1.x; acc[5] += f * e1.y; acc[6] += f * e1.z; acc[7] += f * e1.w;
    }
  }
  float* gd = g + kGoff[l] + ((size_t)b * S + s0 + sl) * 32 + dg * 8;
  ((float4*)gd)[0] = make_float4(acc[0], acc[1], acc[2], acc[3]);
  ((float4*)gd)[1] = make_float4(acc[4], acc[5], acc[6], acc[7]);
}

// ---------------------------------------------------------------------------
// k2: logits GEMV (unified W, contiguous float4 weight loads) + softmax +
// tanh + grid mapping. 32 points/block, emits (w, fx, fy, 0) per sample.
// ---------------------------------------------------------------------------
__global__ __launch_bounds__(256) void k2_logits(
    const float* __restrict__ x,     // (32768, 256)
    const float* __restrict__ ref,   // (32768, 2)
    const float* __restrict__ Wu,    // (256, 96)
    const float* __restrict__ bu,    // (96)
    float4* __restrict__ samp4)      // (32768, 32)
{
  __shared__ float smem[32 * 264];
  const int t = threadIdx.x, blk = blockIdx.x;

  {  // stage 32 x-rows, padded stride 264 floats
    const float4* x4 = (const float4*)x + (size_t)blk * 2048;
    float4* s4 = (float4*)smem;
    #pragma unroll
    for (int q = 0; q < 8; ++q) {
      const int e = q * 256 + t;
      s4[(e >> 6) * 66 + (e & 63)] = x4[e];
    }
  }
  __syncthreads();

  const int jg = t & 7, p = t >> 3, j0 = jg * 12;
  const float* xr = smem + p * 264;
  float acc[12];
  #pragma unroll
  for (int i = 0; i < 12; ++i) acc[i] = bu[j0 + i];
  #pragma unroll 2
  for (int c = 0; c < 256; ++c) {
    const float xa = xr[c];
    const float4* wp = (const float4*)&Wu[c * 96 + j0];
    const float4 w0 = wp[0], w1 = wp[1], w2 = wp[2];
    acc[0] += xa * w0.x; acc[1]  += xa * w0.y; acc[2]  += xa * w0.z; acc[3]  += xa * w0.w;
    acc[4] += xa * w1.x; acc[5]  += xa * w1.y; acc[6]  += xa * w1.z; acc[7]  += xa * w1.w;
    acc[8] += xa * w2.x; acc[9]  += xa * w2.y; acc[10] += xa * w2.z; acc[11] += xa * w2.w;
  }
  __syncthreads();
  float* lg = smem;                  // reuse: logits (32, 96)
  #pragma unroll
  for (int i = 0; i < 12; ++i) lg[p * 96 + j0 + i] = acc[i];
  __syncthreads();

  #pragma unroll
  for (int k = 0; k < 4; ++k) {
    const int slot = k * 256 + t;
    const int pp = slot >> 5, j = slot & 31;
    const int gp = blk * 32 + pp;
    const int l = (gp >> 10) & 3;
    const int Wl = 64 >> l;
    const float* lgp = lg + pp * 96;
    const int h4 = (j >> 2) * 4;
    const float l0 = lgp[h4], l1 = lgp[h4 + 1], l2 = lgp[h4 + 2], l3 = lgp[h4 + 3];
    const float m = fmaxf(fmaxf(l0, l1), fmaxf(l2, l3));
    const float e0 = expf(l0 - m), e1 = expf(l1 - m), e2 = expf(l2 - m), e3 = expf(l3 - m);
    const float inv = 1.f / (e0 + e1 + e2 + e3);
    const float es[4] = {e0, e1, e2, e3};
    const float wj = es[j & 3] * inv;
    const float ox = tanhf(lgp[32 + 2 * j])     + ref[(size_t)gp * 2];
    const float oy = tanhf(lgp[32 + 2 * j + 1]) + ref[(size_t)gp * 2 + 1];
    const float sc = 0.5f * (float)(Wl - 1);
    samp4[(size_t)gp * 32 + j] = make_float4(wj, (ox + 1.f) * sc, (oy + 1.f) * sc, 0.f);
  }
}

// ---------------------------------------------------------------------------
// k3: 16 points/block. Tap precompute (512 slots) -> gather 32-dim projected
// vectors -> weighted sum.  thread = (point-lane t>>6, head (t>>3)&7, dq t&7).
// ---------------------------------------------------------------------------
__global__ __launch_bounds__(256) void k3_main(
    const float* __restrict__ g,
    const float4* __restrict__ samp4,
    const float* __restrict__ embed_b,   // (L, 32)
    float* __restrict__ out)             // (32768, 256)
{
  __shared__ int4   tofs[512];
  __shared__ float4 tws[512];
  const int t = threadIdx.x, blk = blockIdx.x;
  const int l = (blk >> 6) & 3, b = blk >> 8;
  const int Wl = 64 >> l;
  const int gbase = kGoff[l] + b * Wl * Wl * 32;

  #pragma unroll
  for (int q = 0; q < 2; ++q) {
    const int slot = q * 256 + t;
    const float4 s = samp4[(size_t)blk * 512 + slot];
    const float fx = s.y, fy = s.z;
    const float x0f = floorf(fx), y0f = floorf(fy);
    const int x0 = (int)x0f, y0 = (int)y0f, x1 = x0 + 1, y1 = y0 + 1;
    const float wx1 = fx - x0f, wy1 = fy - y0f;
    const float wx0 = 1.f - wx1, wy0 = 1.f - wy1;
    const float xv0 = (x0 >= 0 && x0 < Wl) ? 1.f : 0.f;
    const float xv1 = (x1 >= 0 && x1 < Wl) ? 1.f : 0.f;
    const float yv0 = (y0 >= 0 && y0 < Wl) ? 1.f : 0.f;
    const float yv1 = (y1 >= 0 && y1 < Wl) ? 1.f : 0.f;
    const int x0c = min(max(x0, 0), Wl - 1), x1c = min(max(x1, 0), Wl - 1);
    const int y0c = min(max(y0, 0), Wl - 1), y1c = min(max(y1, 0), Wl - 1);
    tofs[slot] = make_int4(gbase + (y0c * Wl + x0c) * 32,
                           gbase + (y0c * Wl + x1c) * 32,
                           gbase + (y1c * Wl + x0c) * 32,
                           gbase + (y1c * Wl + x1c) * 32);
    const float w = s.x;
    tws[slot] = make_float4(w * wy0 * wx0 * yv0 * xv0,
                            w * wy0 * wx1 * yv0 * xv1,
                            w * wy1 * wx0 * yv1 * xv0,
                            w * wy1 * wx1 * yv1 * xv1);
  }
  __syncthreads();

  const int dq = t & 7, h = (t >> 3) & 7, plg = t >> 6;
  const float4 be = *(const float4*)(embed_b + l * 32 + dq * 4);
  #pragma unroll
  for (int g4 = 0; g4 < 4; ++g4) {
    const int pl = g4 * 4 + plg;
    float4 a = be;
    #pragma unroll
    for (int s = 0; s < 4; ++s) {
      const int slot = pl * 32 + h * 4 + s;
      const int4   o = tofs[slot];
      const float4 w = tws[slot];
      const float4 v00 = *(const float4*)(g + o.x + dq * 4);
      const float4 v01 = *(const float4*)(g + o.y + dq * 4);
      const float4 v10 = *(const float4*)(g + o.z + dq * 4);
      const float4 v11 = *(const float4*)(g + o.w + dq * 4);
      a.x += w.x * v00.x + w.y * v01.x + w.z * v10.x + w.w * v11.x;
      a.y += w.x * v00.y + w.y * v01.y + w.z * v10.y + w.w * v11.y;
      a.z += w.x * v00.z + w.y * v01.z + w.z * v10.z + w.w * v11.z;
      a.w += w.x * v00.w + w.y * v01.w + w.z * v10.w + w.w * v11.w;
    }
    const int gp = blk * 16 + pl;
    *(float4*)(out + (size_t)gp * 256 + h * 32 + dq * 4) = a;
  }
}

// ---------------------------------------------------------------------------
extern "C" void kernel_launch(void* const* d_in, const int* in_sizes, int n_in,
                              void* d_out, int out_size, void* d_ws, size_t ws_size,
                              hipStream_t stream) {
  const float* x      = (const float*)d_in[0];
  const float* ref    = (const float*)d_in[1];
  const float* w_attn = (const float*)d_in[6];
  const float* b_attn = (const float*)d_in[7];
  const float* w_off  = (const float*)d_in[8];
  const float* b_off  = (const float*)d_in[9];
  const float* emb_w  = (const float*)d_in[10];
  const float* emb_b  = (const float*)d_in[11];
  float* ws  = (float*)d_ws;
  float* out = (float*)d_out;

  float*  Wu    = ws + WU_F;
  float*  bu    = ws + BU_F;
  float*  g     = ws + G_F;
  float4* samp4 = (float4*)(ws + SAMP_F);

  k0_unify<<<256, 96, 0, stream>>>(w_attn, b_attn, w_off, b_off, Wu, bu);

  gproj<<<dim3(85, B_), 256, 0, stream>>>(
      (const float*)d_in[2], (const float*)d_in[3],
      (const float*)d_in[4], (const float*)d_in[5], emb_w, g);

  k2_logits<<<B_ * L_ * P_ / 32, 256, 0, stream>>>(x, ref, Wu, bu, samp4);

  k3_main<<<B_ * L_ * P_ / 16, 256, 0, stream>>>(g, samp4, emb_b, out);
}

// Round 4
// 96.235 us; speedup vs baseline: 6.6359x; 1.5757x over previous
//
#include <hip/hip_runtime.h>
#include <math.h>

#define B_   8
#define L_   4
#define P_   1024
#define C_   256
#define NH_  8
#define NS_  4
#define HD_  32

// ws layout (float offsets)
#define G_F     0u          // projected maps (l,b,s,32): 1,392,640 floats
#define SAMP_F  1392640u    // per-sample (w,fx,fy,0) float4: 32768*32*4 floats
#define WU_F    5586944u    // unified W (256,96)
#define BU_F    5611520u    // unified bias (96)

__constant__ const int kGoff[4] = {0, 1048576, 1310720, 1376256};

// ---------------------------------------------------------------------------
// k0: unify [w_attn | w_off] -> Wu (256,96), biases -> bu (96)
// ---------------------------------------------------------------------------
__global__ void k0_unify(const float* __restrict__ wa, const float* __restrict__ ba,
                         const float* __restrict__ wo, const float* __restrict__ bo,
                         float* __restrict__ Wu, float* __restrict__ bu) {
  const int c = blockIdx.x, j = threadIdx.x;
  Wu[c * 96 + j] = (j < 32) ? wa[c * 32 + j] : wo[c * 64 + (j - 32)];
  if (c == 0) bu[j] = (j < 32) ? ba[j] : bo[j - 32];
}

// ---------------------------------------------------------------------------
// gproj: fused transpose+project  g(b,s,:) = feat(b,:,s) @ E_l   (32 outputs)
// ---------------------------------------------------------------------------
__global__ __launch_bounds__(256) void gproj(
    const float* __restrict__ f0, const float* __restrict__ f1,
    const float* __restrict__ f2, const float* __restrict__ f3,
    const float* __restrict__ embed_w, float* __restrict__ g) {
  __shared__ float eL[C_ * HD_];   // 32 KB
  __shared__ float fl[32][64];     // 8 KB
  const int t = threadIdx.x;
  const int b = blockIdx.y;
  int bx = blockIdx.x, l, tile;
  const float* src;
  if (bx < 64)      { l = 0; tile = bx;      src = f0; }
  else if (bx < 80) { l = 1; tile = bx - 64; src = f1; }
  else if (bx < 84) { l = 2; tile = bx - 80; src = f2; }
  else              { l = 3; tile = 0;       src = f3; }
  const int Wl = 64 >> l, S = Wl * Wl;
  const int s0 = tile * 64;

  const float* E = embed_w + (size_t)l * (C_ * HD_);
  #pragma unroll
  for (int q = 0; q < 32; ++q) eL[q * 256 + t] = E[q * 256 + t];

  const float* sb = src + (size_t)b * C_ * S + s0;
  const int sl = t & 63, dg = t >> 6;
  float acc[8];
  #pragma unroll
  for (int e = 0; e < 8; ++e) acc[e] = 0.f;

  for (int c0 = 0; c0 < 256; c0 += 32) {
    __syncthreads();
    #pragma unroll
    for (int q = 0; q < 8; ++q) {
      const int e = q * 256 + t;
      fl[e >> 6][e & 63] = sb[(size_t)(c0 + (e >> 6)) * S + (e & 63)];
    }
    __syncthreads();
    #pragma unroll 8
    for (int ci = 0; ci < 32; ++ci) {
      const float f = fl[ci][sl];
      const float4* ep = (const float4*)&eL[(c0 + ci) * 32 + dg * 8];
      const float4 e0 = ep[0], e1 = ep[1];
      acc[0] += f * e0.x; acc[1] += f * e0.y; acc[2] += f * e0.z; acc[3] += f * e0.w;
      acc[4] += f * e1.x; acc[5] += f * e1.y; acc[6] += f * e1.z; acc[7] += f * e1.w;
    }
  }
  float* gd = g + kGoff[l] + ((size_t)b * S + s0 + sl) * 32 + dg * 8;
  ((float4*)gd)[0] = make_float4(acc[0], acc[1], acc[2], acc[3]);
  ((float4*)gd)[1] = make_float4(acc[4], acc[5], acc[6], acc[7]);
}

// ---------------------------------------------------------------------------
// k2: register-tiled logits GEMM. 128 points/block, K chunked by 64, x and Wu
// staged in LDS. Thread = 4 points (pg + 32i) x 12 outputs (jg*12..+11).
// Then fused softmax + tanh + grid mapping -> samp4.
// ---------------------------------------------------------------------------
#define XS_STR 68   // padded x row stride (floats); 272B = 17*16B (b128-aligned)
__global__ __launch_bounds__(256) void k2_logits(
    const float* __restrict__ x,     // (32768, 256)
    const float* __restrict__ ref,   // (32768, 2)
    const float* __restrict__ Wu,    // (256, 96)
    const float* __restrict__ bu,    // (96)
    float4* __restrict__ samp4)      // (32768, 32)
{
  __shared__ float sm[128 * XS_STR + 64 * 96];   // 59.4 KB; reused for logits
  float* sm_x = sm;                  // [128][XS_STR]
  float* sm_w = sm + 128 * XS_STR;   // [64][96]

  const int t = threadIdx.x, blk = blockIdx.x;   // 256 blocks
  const int jg = t & 7;              // output group: j = jg*12 + 0..11
  const int pg = t >> 3;             // point lanes: p = pg + 32*i

  float acc[4][12];
  #pragma unroll
  for (int i = 0; i < 4; ++i)
    #pragma unroll
    for (int j = 0; j < 12; ++j) acc[i][j] = bu[jg * 12 + j];

  for (int chunk = 0; chunk < 4; ++chunk) {
    const int c0 = chunk * 64;
    __syncthreads();
    // stage x[blk*128 .. +128][c0..c0+64)  (8 float4 per thread, coalesced)
    {
      const int c4 = t & 15, pr = t >> 4;
      #pragma unroll
      for (int q = 0; q < 8; ++q) {
        const int p = q * 16 + pr;
        const float4 v = *(const float4*)(x + (size_t)(blk * 128 + p) * 256 + c0 + c4 * 4);
        *(float4*)(sm_x + p * XS_STR + c4 * 4) = v;
      }
    }
    // stage Wu[c0..c0+64)[0..96) : 1536 float4, linear, coalesced
    {
      const float4* srcw = (const float4*)(Wu + c0 * 96);
      float4* dstw = (float4*)sm_w;
      #pragma unroll
      for (int q = 0; q < 6; ++q) dstw[q * 256 + t] = srcw[q * 256 + t];
    }
    __syncthreads();

    for (int cc = 0; cc < 64; ++cc) {
      const float4* wp = (const float4*)(sm_w + cc * 96 + jg * 12);
      const float4 w0 = wp[0], w1 = wp[1], w2 = wp[2];
      float xv[4];
      #pragma unroll
      for (int i = 0; i < 4; ++i) xv[i] = sm_x[(pg + 32 * i) * XS_STR + cc];
      #pragma unroll
      for (int i = 0; i < 4; ++i) {
        const float xa = xv[i];
        acc[i][0] += xa * w0.x; acc[i][1]  += xa * w0.y; acc[i][2]  += xa * w0.z; acc[i][3]  += xa * w0.w;
        acc[i][4] += xa * w1.x; acc[i][5]  += xa * w1.y; acc[i][6]  += xa * w1.z; acc[i][7]  += xa * w1.w;
        acc[i][8] += xa * w2.x; acc[i][9]  += xa * w2.y; acc[i][10] += xa * w2.z; acc[i][11] += xa * w2.w;
      }
    }
  }
  __syncthreads();

  // write logits (128, 96) into sm (reuse)
  float* lg = sm;
  #pragma unroll
  for (int i = 0; i < 4; ++i) {
    float2* dst = (float2*)(lg + (pg + 32 * i) * 96 + jg * 12);
    dst[0] = make_float2(acc[i][0],  acc[i][1]);
    dst[1] = make_float2(acc[i][2],  acc[i][3]);
    dst[2] = make_float2(acc[i][4],  acc[i][5]);
    dst[3] = make_float2(acc[i][6],  acc[i][7]);
    dst[4] = make_float2(acc[i][8],  acc[i][9]);
    dst[5] = make_float2(acc[i][10], acc[i][11]);
  }
  __syncthreads();

  // softmax + tanh + grid mapping: 4096 slots, 16 per thread
  #pragma unroll
  for (int k = 0; k < 16; ++k) {
    const int slot = k * 256 + t;
    const int pp = slot >> 5, j = slot & 31;
    const int gp = blk * 128 + pp;
    const int l = (gp >> 10) & 3;
    const int Wl = 64 >> l;
    const float* lgp = lg + pp * 96;
    const int h4 = (j >> 2) * 4;
    const float l0 = lgp[h4], l1 = lgp[h4 + 1], l2 = lgp[h4 + 2], l3 = lgp[h4 + 3];
    const float m = fmaxf(fmaxf(l0, l1), fmaxf(l2, l3));
    const float e0 = expf(l0 - m), e1 = expf(l1 - m), e2 = expf(l2 - m), e3 = expf(l3 - m);
    const float inv = 1.f / (e0 + e1 + e2 + e3);
    const float es[4] = {e0, e1, e2, e3};
    const float wj = es[j & 3] * inv;
    const float ox = tanhf(lgp[32 + 2 * j])     + ref[(size_t)gp * 2];
    const float oy = tanhf(lgp[32 + 2 * j + 1]) + ref[(size_t)gp * 2 + 1];
    const float sc = 0.5f * (float)(Wl - 1);
    samp4[(size_t)gp * 32 + j] = make_float4(wj, (ox + 1.f) * sc, (oy + 1.f) * sc, 0.f);
  }
}

// ---------------------------------------------------------------------------
// k3: 16 points/block. Tap precompute -> gather 32-dim projected vectors.
// ---------------------------------------------------------------------------
__global__ __launch_bounds__(256) void k3_main(
    const float* __restrict__ g,
    const float4* __restrict__ samp4,
    const float* __restrict__ embed_b,   // (L, 32)
    float* __restrict__ out)             // (32768, 256)
{
  __shared__ int4   tofs[512];
  __shared__ float4 tws[512];
  const int t = threadIdx.x, blk = blockIdx.x;
  const int l = (blk >> 6) & 3, b = blk >> 8;
  const int Wl = 64 >> l;
  const int gbase = kGoff[l] + b * Wl * Wl * 32;

  #pragma unroll
  for (int q = 0; q < 2; ++q) {
    const int slot = q * 256 + t;
    const float4 s = samp4[(size_t)blk * 512 + slot];
    const float fx = s.y, fy = s.z;
    const float x0f = floorf(fx), y0f = floorf(fy);
    const int x0 = (int)x0f, y0 = (int)y0f, x1 = x0 + 1, y1 = y0 + 1;
    const float wx1 = fx - x0f, wy1 = fy - y0f;
    const float wx0 = 1.f - wx1, wy0 = 1.f - wy1;
    const float xv0 = (x0 >= 0 && x0 < Wl) ? 1.f : 0.f;
    const float xv1 = (x1 >= 0 && x1 < Wl) ? 1.f : 0.f;
    const float yv0 = (y0 >= 0 && y0 < Wl) ? 1.f : 0.f;
    const float yv1 = (y1 >= 0 && y1 < Wl) ? 1.f : 0.f;
    const int x0c = min(max(x0, 0), Wl - 1), x1c = min(max(x1, 0), Wl - 1);
    const int y0c = min(max(y0, 0), Wl - 1), y1c = min(max(y1, 0), Wl - 1);
    tofs[slot] = make_int4(gbase + (y0c * Wl + x0c) * 32,
                           gbase + (y0c * Wl + x1c) * 32,
                           gbase + (y1c * Wl + x0c) * 32,
                           gbase + (y1c * Wl + x1c) * 32);
    const float w = s.x;
    tws[slot] = make_float4(w * wy0 * wx0 * yv0 * xv0,
                            w * wy0 * wx1 * yv0 * xv1,
                            w * wy1 * wx0 * yv1 * xv0,
                            w * wy1 * wx1 * yv1 * xv1);
  }
  __syncthreads();

  const int dq = t & 7, h = (t >> 3) & 7, plg = t >> 6;
  const float4 be = *(const float4*)(embed_b + l * 32 + dq * 4);
  #pragma unroll
  for (int g4 = 0; g4 < 4; ++g4) {
    const int pl = g4 * 4 + plg;
    float4 a = be;
    #pragma unroll
    for (int s = 0; s < 4; ++s) {
      const int slot = pl * 32 + h * 4 + s;
      const int4   o = tofs[slot];
      const float4 w = tws[slot];
      const float4 v00 = *(const float4*)(g + o.x + dq * 4);
      const float4 v01 = *(const float4*)(g + o.y + dq * 4);
      const float4 v10 = *(const float4*)(g + o.z + dq * 4);
      const float4 v11 = *(const float4*)(g + o.w + dq * 4);
      a.x += w.x * v00.x + w.y * v01.x + w.z * v10.x + w.w * v11.x;
      a.y += w.x * v00.y + w.y * v01.y + w.z * v10.y + w.w * v11.y;
      a.z += w.x * v00.z + w.y * v01.z + w.z * v10.z + w.w * v11.z;
      a.w += w.x * v00.w + w.y * v01.w + w.z * v10.w + w.w * v11.w;
    }
    const int gp = blk * 16 + pl;
    *(float4*)(out + (size_t)gp * 256 + h * 32 + dq * 4) = a;
  }
}

// ---------------------------------------------------------------------------
extern "C" void kernel_launch(void* const* d_in, const int* in_sizes, int n_in,
                              void* d_out, int out_size, void* d_ws, size_t ws_size,
                              hipStream_t stream) {
  const float* x      = (const float*)d_in[0];
  const float* ref    = (const float*)d_in[1];
  const float* w_attn = (const float*)d_in[6];
  const float* b_attn = (const float*)d_in[7];
  const float* w_off  = (const float*)d_in[8];
  const float* b_off  = (const float*)d_in[9];
  const float* emb_w  = (const float*)d_in[10];
  const float* emb_b  = (const float*)d_in[11];
  float* ws  = (float*)d_ws;
  float* out = (float*)d_out;

  float*  Wu    = ws + WU_F;
  float*  bu    = ws + BU_F;
  float*  g     = ws + G_F;
  float4* samp4 = (float4*)(ws + SAMP_F);

  k0_unify<<<256, 96, 0, stream>>>(w_attn, b_attn, w_off, b_off, Wu, bu);

  gproj<<<dim3(85, B_), 256, 0, stream>>>(
      (const float*)d_in[2], (const float*)d_in[3],
      (const float*)d_in[4], (const float*)d_in[5], emb_w, g);

  k2_logits<<<B_ * L_ * P_ / 128, 256, 0, stream>>>(x, ref, Wu, bu, samp4);

  k3_main<<<B_ * L_ * P_ / 16, 256, 0, stream>>>(g, samp4, emb_b, out);
}

// Round 5
// 94.185 us; speedup vs baseline: 6.7803x; 1.0218x over previous
//
#include <hip/hip_runtime.h>
#include <math.h>

#define B_   8
#define L_   4
#define P_   1024
#define C_   256
#define NH_  8
#define NS_  4
#define HD_  32

// ws layout (float offsets)
#define G_F     0u          // projected maps (l,b,s,32): 1,392,640 floats
#define SAMP_F  1392640u    // per-sample (w,fx,fy,0) float4: 32768*32*4 floats
#define WU_F    5586944u    // unified W (256,96)
#define BU_F    5611520u    // unified bias (96)

__constant__ const int kGoff[4] = {0, 1048576, 1310720, 1376256};

// ---------------------------------------------------------------------------
// k0: unify [w_attn | w_off] -> Wu (256,96), biases -> bu (96)
// ---------------------------------------------------------------------------
__global__ void k0_unify(const float* __restrict__ wa, const float* __restrict__ ba,
                         const float* __restrict__ wo, const float* __restrict__ bo,
                         float* __restrict__ Wu, float* __restrict__ bu) {
  const int c = blockIdx.x, j = threadIdx.x;
  Wu[c * 96 + j] = (j < 32) ? wa[c * 32 + j] : wo[c * 64 + (j - 32)];
  if (c == 0) bu[j] = (j < 32) ? ba[j] : bo[j - 32];
}

// ---------------------------------------------------------------------------
// gproj: fused transpose+project  g(b,s,:) = feat(b,:,s) @ E_l   (32 outputs)
// ---------------------------------------------------------------------------
__global__ __launch_bounds__(256) void gproj(
    const float* __restrict__ f0, const float* __restrict__ f1,
    const float* __restrict__ f2, const float* __restrict__ f3,
    const float* __restrict__ embed_w, float* __restrict__ g) {
  __shared__ float eL[C_ * HD_];   // 32 KB
  __shared__ float fl[32][64];     // 8 KB
  const int t = threadIdx.x;
  const int b = blockIdx.y;
  int bx = blockIdx.x, l, tile;
  const float* src;
  if (bx < 64)      { l = 0; tile = bx;      src = f0; }
  else if (bx < 80) { l = 1; tile = bx - 64; src = f1; }
  else if (bx < 84) { l = 2; tile = bx - 80; src = f2; }
  else              { l = 3; tile = 0;       src = f3; }
  const int Wl = 64 >> l, S = Wl * Wl;
  const int s0 = tile * 64;

  const float* E = embed_w + (size_t)l * (C_ * HD_);
  #pragma unroll
  for (int q = 0; q < 32; ++q) eL[q * 256 + t] = E[q * 256 + t];

  const float* sb = src + (size_t)b * C_ * S + s0;
  const int sl = t & 63, dg = t >> 6;
  float acc[8];
  #pragma unroll
  for (int e = 0; e < 8; ++e) acc[e] = 0.f;

  for (int c0 = 0; c0 < 256; c0 += 32) {
    __syncthreads();
    #pragma unroll
    for (int q = 0; q < 8; ++q) {
      const int e = q * 256 + t;
      fl[e >> 6][e & 63] = sb[(size_t)(c0 + (e >> 6)) * S + (e & 63)];
    }
    __syncthreads();
    #pragma unroll 8
    for (int ci = 0; ci < 32; ++ci) {
      const float f = fl[ci][sl];
      const float4* ep = (const float4*)&eL[(c0 + ci) * 32 + dg * 8];
      const float4 e0 = ep[0], e1 = ep[1];
      acc[0] += f * e0.x; acc[1] += f * e0.y; acc[2] += f * e0.z; acc[3] += f * e0.w;
      acc[4] += f * e1.x; acc[5] += f * e1.y; acc[6] += f * e1.z; acc[7] += f * e1.w;
    }
  }
  float* gd = g + kGoff[l] + ((size_t)b * S + s0 + sl) * 32 + dg * 8;
  ((float4*)gd)[0] = make_float4(acc[0], acc[1], acc[2], acc[3]);
  ((float4*)gd)[1] = make_float4(acc[4], acc[5], acc[6], acc[7]);
}

// ---------------------------------------------------------------------------
// k2: register-tiled logits GEMM. 64 points/block (512 blocks, 3 blocks/CU),
// K chunked by 64, x and Wu in LDS, inner loop unrolled 4 K-steps with b128
// x reads. Thread = 2 points (pg, pg+32) x 12 outputs (jg*12..+11).
// ---------------------------------------------------------------------------
#define XS_STR 68   // padded x row stride (floats); 272B = 17*16B (b128-aligned)
__global__ __launch_bounds__(256) void k2_logits(
    const float* __restrict__ x,     // (32768, 256)
    const float* __restrict__ ref,   // (32768, 2)
    const float* __restrict__ Wu,    // (256, 96)
    const float* __restrict__ bu,    // (96)
    float4* __restrict__ samp4)      // (32768, 32)
{
  __shared__ float sm[64 * XS_STR + 64 * 96];   // 42 KB; reused for logits
  float* sm_x = sm;                 // [64][XS_STR]
  float* sm_w = sm + 64 * XS_STR;   // [64][96]

  const int t = threadIdx.x, blk = blockIdx.x;   // 512 blocks
  const int jg = t & 7;             // output group: j = jg*12 + 0..11
  const int pg = t >> 3;            // point lanes: p = pg, pg+32

  float acc[2][12];
  #pragma unroll
  for (int i = 0; i < 2; ++i)
    #pragma unroll
    for (int j = 0; j < 12; ++j) acc[i][j] = bu[jg * 12 + j];

  for (int chunk = 0; chunk < 4; ++chunk) {
    const int c0 = chunk * 64;
    __syncthreads();
    // stage x[blk*64 .. +64][c0..c0+64): 4 float4/thread, coalesced
    {
      const int c4 = t & 15, pr = t >> 4;
      #pragma unroll
      for (int q = 0; q < 4; ++q) {
        const int p = q * 16 + pr;
        const float4 v = *(const float4*)(x + (size_t)(blk * 64 + p) * 256 + c0 + c4 * 4);
        *(float4*)(sm_x + p * XS_STR + c4 * 4) = v;
      }
    }
    // stage Wu[c0..c0+64)[0..96): 1536 float4, linear, coalesced
    {
      const float4* srcw = (const float4*)(Wu + c0 * 96);
      float4* dstw = (float4*)sm_w;
      #pragma unroll
      for (int q = 0; q < 6; ++q) dstw[q * 256 + t] = srcw[q * 256 + t];
    }
    __syncthreads();

    #pragma unroll 4
    for (int cc4 = 0; cc4 < 16; ++cc4) {
      const float4 xa4 = *(const float4*)(sm_x + pg * XS_STR + cc4 * 4);
      const float4 xb4 = *(const float4*)(sm_x + (pg + 32) * XS_STR + cc4 * 4);
      const float xav[4] = {xa4.x, xa4.y, xa4.z, xa4.w};
      const float xbv[4] = {xb4.x, xb4.y, xb4.z, xb4.w};
      #pragma unroll
      for (int k = 0; k < 4; ++k) {
        const float4* wp = (const float4*)(sm_w + (cc4 * 4 + k) * 96 + jg * 12);
        const float4 w0 = wp[0], w1 = wp[1], w2 = wp[2];
        const float xa = xav[k], xb = xbv[k];
        acc[0][0] += xa * w0.x; acc[0][1]  += xa * w0.y; acc[0][2]  += xa * w0.z; acc[0][3]  += xa * w0.w;
        acc[0][4] += xa * w1.x; acc[0][5]  += xa * w1.y; acc[0][6]  += xa * w1.z; acc[0][7]  += xa * w1.w;
        acc[0][8] += xa * w2.x; acc[0][9]  += xa * w2.y; acc[0][10] += xa * w2.z; acc[0][11] += xa * w2.w;
        acc[1][0] += xb * w0.x; acc[1][1]  += xb * w0.y; acc[1][2]  += xb * w0.z; acc[1][3]  += xb * w0.w;
        acc[1][4] += xb * w1.x; acc[1][5]  += xb * w1.y; acc[1][6]  += xb * w1.z; acc[1][7]  += xb * w1.w;
        acc[1][8] += xb * w2.x; acc[1][9]  += xb * w2.y; acc[1][10] += xb * w2.z; acc[1][11] += xb * w2.w;
      }
    }
  }
  __syncthreads();

  // write logits (64, 96) into sm (reuse)
  float* lg = sm;
  #pragma unroll
  for (int i = 0; i < 2; ++i) {
    float2* dst = (float2*)(lg + (pg + 32 * i) * 96 + jg * 12);
    dst[0] = make_float2(acc[i][0],  acc[i][1]);
    dst[1] = make_float2(acc[i][2],  acc[i][3]);
    dst[2] = make_float2(acc[i][4],  acc[i][5]);
    dst[3] = make_float2(acc[i][6],  acc[i][7]);
    dst[4] = make_float2(acc[i][8],  acc[i][9]);
    dst[5] = make_float2(acc[i][10], acc[i][11]);
  }
  __syncthreads();

  // softmax + tanh + grid mapping: 2048 slots, 8 per thread
  #pragma unroll
  for (int k = 0; k < 8; ++k) {
    const int slot = k * 256 + t;
    const int pp = slot >> 5, j = slot & 31;
    const int gp = blk * 64 + pp;
    const int l = (gp >> 10) & 3;
    const int Wl = 64 >> l;
    const float* lgp = lg + pp * 96;
    const int h4 = (j >> 2) * 4;
    const float l0 = lgp[h4], l1 = lgp[h4 + 1], l2 = lgp[h4 + 2], l3 = lgp[h4 + 3];
    const float m = fmaxf(fmaxf(l0, l1), fmaxf(l2, l3));
    const float e0 = expf(l0 - m), e1 = expf(l1 - m), e2 = expf(l2 - m), e3 = expf(l3 - m);
    const float inv = 1.f / (e0 + e1 + e2 + e3);
    const float es[4] = {e0, e1, e2, e3};
    const float wj = es[j & 3] * inv;
    const float ox = tanhf(lgp[32 + 2 * j])     + ref[(size_t)gp * 2];
    const float oy = tanhf(lgp[32 + 2 * j + 1]) + ref[(size_t)gp * 2 + 1];
    const float sc = 0.5f * (float)(Wl - 1);
    samp4[(size_t)gp * 32 + j] = make_float4(wj, (ox + 1.f) * sc, (oy + 1.f) * sc, 0.f);
  }
}

// ---------------------------------------------------------------------------
// k3: 16 points/block. Tap precompute -> gather 32-dim projected vectors.
// ---------------------------------------------------------------------------
__global__ __launch_bounds__(256) void k3_main(
    const float* __restrict__ g,
    const float4* __restrict__ samp4,
    const float* __restrict__ embed_b,   // (L, 32)
    float* __restrict__ out)             // (32768, 256)
{
  __shared__ int4   tofs[512];
  __shared__ float4 tws[512];
  const int t = threadIdx.x, blk = blockIdx.x;
  const int l = (blk >> 6) & 3, b = blk >> 8;
  const int Wl = 64 >> l;
  const int gbase = kGoff[l] + b * Wl * Wl * 32;

  #pragma unroll
  for (int q = 0; q < 2; ++q) {
    const int slot = q * 256 + t;
    const float4 s = samp4[(size_t)blk * 512 + slot];
    const float fx = s.y, fy = s.z;
    const float x0f = floorf(fx), y0f = floorf(fy);
    const int x0 = (int)x0f, y0 = (int)y0f, x1 = x0 + 1, y1 = y0 + 1;
    const float wx1 = fx - x0f, wy1 = fy - y0f;
    const float wx0 = 1.f - wx1, wy0 = 1.f - wy1;
    const float xv0 = (x0 >= 0 && x0 < Wl) ? 1.f : 0.f;
    const float xv1 = (x1 >= 0 && x1 < Wl) ? 1.f : 0.f;
    const float yv0 = (y0 >= 0 && y0 < Wl) ? 1.f : 0.f;
    const float yv1 = (y1 >= 0 && y1 < Wl) ? 1.f : 0.f;
    const int x0c = min(max(x0, 0), Wl - 1), x1c = min(max(x1, 0), Wl - 1);
    const int y0c = min(max(y0, 0), Wl - 1), y1c = min(max(y1, 0), Wl - 1);
    tofs[slot] = make_int4(gbase + (y0c * Wl + x0c) * 32,
                           gbase + (y0c * Wl + x1c) * 32,
                           gbase + (y1c * Wl + x0c) * 32,
                           gbase + (y1c * Wl + x1c) * 32);
    const float w = s.x;
    tws[slot] = make_float4(w * wy0 * wx0 * yv0 * xv0,
                            w * wy0 * wx1 * yv0 * xv1,
                            w * wy1 * wx0 * yv1 * xv0,
                            w * wy1 * wx1 * yv1 * xv1);
  }
  __syncthreads();

  const int dq = t & 7, h = (t >> 3) & 7, plg = t >> 6;
  const float4 be = *(const float4*)(embed_b + l * 32 + dq * 4);
  #pragma unroll
  for (int g4 = 0; g4 < 4; ++g4) {
    const int pl = g4 * 4 + plg;
    float4 a = be;
    #pragma unroll
    for (int s = 0; s < 4; ++s) {
      const int slot = pl * 32 + h * 4 + s;
      const int4   o = tofs[slot];
      const float4 w = tws[slot];
      const float4 v00 = *(const float4*)(g + o.x + dq * 4);
      const float4 v01 = *(const float4*)(g + o.y + dq * 4);
      const float4 v10 = *(const float4*)(g + o.z + dq * 4);
      const float4 v11 = *(const float4*)(g + o.w + dq * 4);
      a.x += w.x * v00.x + w.y * v01.x + w.z * v10.x + w.w * v11.x;
      a.y += w.x * v00.y + w.y * v01.y + w.z * v10.y + w.w * v11.y;
      a.z += w.x * v00.z + w.y * v01.z + w.z * v10.z + w.w * v11.z;
      a.w += w.x * v00.w + w.y * v01.w + w.z * v10.w + w.w * v11.w;
    }
    const int gp = blk * 16 + pl;
    *(float4*)(out + (size_t)gp * 256 + h * 32 + dq * 4) = a;
  }
}

// ---------------------------------------------------------------------------
extern "C" void kernel_launch(void* const* d_in, const int* in_sizes, int n_in,
                              void* d_out, int out_size, void* d_ws, size_t ws_size,
                              hipStream_t stream) {
  const float* x      = (const float*)d_in[0];
  const float* ref    = (const float*)d_in[1];
  const float* w_attn = (const float*)d_in[6];
  const float* b_attn = (const float*)d_in[7];
  const float* w_off  = (const float*)d_in[8];
  const float* b_off  = (const float*)d_in[9];
  const float* emb_w  = (const float*)d_in[10];
  const float* emb_b  = (const float*)d_in[11];
  float* ws  = (float*)d_ws;
  float* out = (float*)d_out;

  float*  Wu    = ws + WU_F;
  float*  bu    = ws + BU_F;
  float*  g     = ws + G_F;
  float4* samp4 = (float4*)(ws + SAMP_F);

  k0_unify<<<256, 96, 0, stream>>>(w_attn, b_attn, w_off, b_off, Wu, bu);

  gproj<<<dim3(85, B_), 256, 0, stream>>>(
      (const float*)d_in[2], (const float*)d_in[3],
      (const float*)d_in[4], (const float*)d_in[5], emb_w, g);

  k2_logits<<<B_ * L_ * P_ / 64, 256, 0, stream>>>(x, ref, Wu, bu, samp4);

  k3_main<<<B_ * L_ * P_ / 16, 256, 0, stream>>>(g, samp4, emb_b, out);
}

// Round 6
// 75.131 us; speedup vs baseline: 8.4999x; 1.2536x over previous
//
#include <hip/hip_runtime.h>
#include <math.h>

#define B_   8
#define L_   4
#define P_   1024
#define C_   256
#define NH_  8
#define NS_  4
#define HD_  32

typedef _Float16 half8 __attribute__((ext_vector_type(8)));
typedef float    f32x4 __attribute__((ext_vector_type(4)));

// ws layout (float offsets)
#define G_F     0u          // projected maps (l,b,s,32): 1,392,640 floats
#define SAMP_F  1392640u    // per-sample (w,fx,fy,0) float4: 32768*32*4 floats
#define WU_F    5586944u    // WuT fp16 (96,256) -> 12288 float slots
#define BU_F    5611520u    // unified bias (96)

__constant__ const int kGoff[4] = {0, 1048576, 1310720, 1376256};

// ---------------------------------------------------------------------------
// k0: build WuT fp16 (96, 256) K-major + fp32 bias bu(96)
// ---------------------------------------------------------------------------
__global__ void k0_unify(const float* __restrict__ wa, const float* __restrict__ ba,
                         const float* __restrict__ wo, const float* __restrict__ bo,
                         _Float16* __restrict__ WuT, float* __restrict__ bu) {
  const int n = blockIdx.x;    // 0..95
  const int c = threadIdx.x;   // 0..255
  const float v = (n < 32) ? wa[c * 32 + n] : wo[c * 64 + (n - 32)];
  WuT[n * 256 + c] = (_Float16)v;
  if (n == 0 && c < 96) bu[c] = (c < 32) ? ba[c] : bo[c - 32];
}

// ---------------------------------------------------------------------------
// gproj: fused transpose+project  g(b,s,:) = feat(b,:,s) @ E_l   (32 outputs)
// ---------------------------------------------------------------------------
__global__ __launch_bounds__(256) void gproj(
    const float* __restrict__ f0, const float* __restrict__ f1,
    const float* __restrict__ f2, const float* __restrict__ f3,
    const float* __restrict__ embed_w, float* __restrict__ g) {
  __shared__ float eL[C_ * HD_];   // 32 KB
  __shared__ float fl[32][64];     // 8 KB
  const int t = threadIdx.x;
  const int b = blockIdx.y;
  int bx = blockIdx.x, l, tile;
  const float* src;
  if (bx < 64)      { l = 0; tile = bx;      src = f0; }
  else if (bx < 80) { l = 1; tile = bx - 64; src = f1; }
  else if (bx < 84) { l = 2; tile = bx - 80; src = f2; }
  else              { l = 3; tile = 0;       src = f3; }
  const int Wl = 64 >> l, S = Wl * Wl;
  const int s0 = tile * 64;

  const float* E = embed_w + (size_t)l * (C_ * HD_);
  #pragma unroll
  for (int q = 0; q < 32; ++q) eL[q * 256 + t] = E[q * 256 + t];

  const float* sb = src + (size_t)b * C_ * S + s0;
  const int sl = t & 63, dg = t >> 6;
  float acc[8];
  #pragma unroll
  for (int e = 0; e < 8; ++e) acc[e] = 0.f;

  for (int c0 = 0; c0 < 256; c0 += 32) {
    __syncthreads();
    #pragma unroll
    for (int q = 0; q < 8; ++q) {
      const int e = q * 256 + t;
      fl[e >> 6][e & 63] = sb[(size_t)(c0 + (e >> 6)) * S + (e & 63)];
    }
    __syncthreads();
    #pragma unroll 8
    for (int ci = 0; ci < 32; ++ci) {
      const float f = fl[ci][sl];
      const float4* ep = (const float4*)&eL[(c0 + ci) * 32 + dg * 8];
      const float4 e0 = ep[0], e1 = ep[1];
      acc[0] += f * e0.x; acc[1] += f * e0.y; acc[2] += f * e0.z; acc[3] += f * e0.w;
      acc[4] += f * e1.x; acc[5] += f * e1.y; acc[6] += f * e1.z; acc[7] += f * e1.w;
    }
  }
  float* gd = g + kGoff[l] + ((size_t)b * S + s0 + sl) * 32 + dg * 8;
  ((float4*)gd)[0] = make_float4(acc[0], acc[1], acc[2], acc[3]);
  ((float4*)gd)[1] = make_float4(acc[4], acc[5], acc[6], acc[7]);
}

// ---------------------------------------------------------------------------
// k2: MFMA logits GEMM (fp16 in, fp32 acc). 64 points/block (512 blocks),
// 4 waves; wave w computes pts [w*16, w*16+16) x all 96 outs.
// K chunked by 128; x and WuT staged in LDS with padded stride 136 halves.
// Then fused softmax + tanh + grid mapping -> samp4.
// ---------------------------------------------------------------------------
#define XH 136          // padded half stride (272 B = 17*16 B)
#define LGS 100         // logits row stride (floats)
__global__ __launch_bounds__(256) void k2_logits(
    const float*    __restrict__ x,     // (32768, 256)
    const float*    __restrict__ ref,   // (32768, 2)
    const _Float16* __restrict__ WuT,   // (96, 256) K-major
    const float*    __restrict__ bu,    // (96)
    float4*         __restrict__ samp4) // (32768, 32)
{
  __shared__ float4 smraw4[2720];       // 43520 B, overlaid below
  _Float16* smx = (_Float16*)smraw4;            // [64][XH]
  _Float16* smw = (_Float16*)smraw4 + 64 * XH;  // [96][XH]
  float*    lg  = (float*)smraw4;               // [64][LGS] (reused after GEMM)

  const int t = threadIdx.x, blk = blockIdx.x;  // 512 blocks
  const int lane = t & 63, w = t >> 6;
  const int lr = lane & 15, kg = lane >> 4;

  f32x4 acc[6];
  #pragma unroll
  for (int nt = 0; nt < 6; ++nt) acc[nt] = (f32x4){0.f, 0.f, 0.f, 0.f};

  #pragma unroll
  for (int chunk = 0; chunk < 2; ++chunk) {
    const int c0 = chunk * 128;
    if (chunk) __syncthreads();
    // stage x: thread = (pt = t>>2, q = t&3), 32 floats -> 32 halves
    {
      const int pt = t >> 2, q = t & 3;
      const float4* src = (const float4*)(x + (size_t)(blk * 64 + pt) * 256 + c0 + q * 32);
      _Float16* dst = smx + pt * XH + q * 32;
      #pragma unroll
      for (int i = 0; i < 4; ++i) {
        const float4 v0 = src[2 * i], v1 = src[2 * i + 1];
        half8 h = {(_Float16)v0.x, (_Float16)v0.y, (_Float16)v0.z, (_Float16)v0.w,
                   (_Float16)v1.x, (_Float16)v1.y, (_Float16)v1.z, (_Float16)v1.w};
        *(half8*)(dst + i * 8) = h;
      }
    }
    // stage WuT: 192 threads, thread = (n = t>>1, half 64-halves), 8 half8 each
    if (t < 192) {
      const int n = t >> 1, ho = (t & 1) * 64;
      const float4* src = (const float4*)(WuT + (size_t)n * 256 + c0 + ho);
      float4* dst = (float4*)(smw + n * XH + ho);
      #pragma unroll
      for (int i = 0; i < 8; ++i) dst[i] = src[i];
    }
    __syncthreads();

    #pragma unroll
    for (int ks = 0; ks < 4; ++ks) {
      const half8 a = *(const half8*)(smx + (w * 16 + lr) * XH + ks * 32 + kg * 8);
      #pragma unroll
      for (int nt = 0; nt < 6; ++nt) {
        const half8 bf = *(const half8*)(smw + (nt * 16 + lr) * XH + ks * 32 + kg * 8);
        acc[nt] = __builtin_amdgcn_mfma_f32_16x16x32_f16(a, bf, acc[nt], 0, 0, 0);
      }
    }
  }
  __syncthreads();

  // spill accumulators (+bias) to lg[64][LGS]: D col = lane&15, row = kg*4+r
  #pragma unroll
  for (int nt = 0; nt < 6; ++nt) {
    const int n = nt * 16 + lr;
    const float bv = bu[n];
    #pragma unroll
    for (int r = 0; r < 4; ++r)
      lg[(w * 16 + kg * 4 + r) * LGS + n] = acc[nt][r] + bv;
  }
  __syncthreads();

  // softmax + tanh + grid mapping: 2048 slots, 8 per thread
  #pragma unroll
  for (int k = 0; k < 8; ++k) {
    const int slot = k * 256 + t;
    const int pp = slot >> 5, j = slot & 31;
    const int gp = blk * 64 + pp;
    const int l = (gp >> 10) & 3;
    const int Wl = 64 >> l;
    const float* lgp = lg + pp * LGS;
    const int h4 = (j >> 2) * 4;
    const float l0 = lgp[h4], l1 = lgp[h4 + 1], l2 = lgp[h4 + 2], l3 = lgp[h4 + 3];
    const float m = fmaxf(fmaxf(l0, l1), fmaxf(l2, l3));
    const float e0 = expf(l0 - m), e1 = expf(l1 - m), e2 = expf(l2 - m), e3 = expf(l3 - m);
    const float inv = 1.f / (e0 + e1 + e2 + e3);
    const float es[4] = {e0, e1, e2, e3};
    const float wj = es[j & 3] * inv;
    const float ox = tanhf(lgp[32 + 2 * j])     + ref[(size_t)gp * 2];
    const float oy = tanhf(lgp[32 + 2 * j + 1]) + ref[(size_t)gp * 2 + 1];
    const float sc = 0.5f * (float)(Wl - 1);
    samp4[(size_t)gp * 32 + j] = make_float4(wj, (ox + 1.f) * sc, (oy + 1.f) * sc, 0.f);
  }
}

// ---------------------------------------------------------------------------
// k3: 16 points/block. Tap precompute -> gather 32-dim projected vectors.
// ---------------------------------------------------------------------------
__global__ __launch_bounds__(256) void k3_main(
    const float* __restrict__ g,
    const float4* __restrict__ samp4,
    const float* __restrict__ embed_b,   // (L, 32)
    float* __restrict__ out)             // (32768, 256)
{
  __shared__ int4   tofs[512];
  __shared__ float4 tws[512];
  const int t = threadIdx.x, blk = blockIdx.x;
  const int l = (blk >> 6) & 3, b = blk >> 8;
  const int Wl = 64 >> l;
  const int gbase = kGoff[l] + b * Wl * Wl * 32;

  #pragma unroll
  for (int q = 0; q < 2; ++q) {
    const int slot = q * 256 + t;
    const float4 s = samp4[(size_t)blk * 512 + slot];
    const float fx = s.y, fy = s.z;
    const float x0f = floorf(fx), y0f = floorf(fy);
    const int x0 = (int)x0f, y0 = (int)y0f, x1 = x0 + 1, y1 = y0 + 1;
    const float wx1 = fx - x0f, wy1 = fy - y0f;
    const float wx0 = 1.f - wx1, wy0 = 1.f - wy1;
    const float xv0 = (x0 >= 0 && x0 < Wl) ? 1.f : 0.f;
    const float xv1 = (x1 >= 0 && x1 < Wl) ? 1.f : 0.f;
    const float yv0 = (y0 >= 0 && y0 < Wl) ? 1.f : 0.f;
    const float yv1 = (y1 >= 0 && y1 < Wl) ? 1.f : 0.f;
    const int x0c = min(max(x0, 0), Wl - 1), x1c = min(max(x1, 0), Wl - 1);
    const int y0c = min(max(y0, 0), Wl - 1), y1c = min(max(y1, 0), Wl - 1);
    tofs[slot] = make_int4(gbase + (y0c * Wl + x0c) * 32,
                           gbase + (y0c * Wl + x1c) * 32,
                           gbase + (y1c * Wl + x0c) * 32,
                           gbase + (y1c * Wl + x1c) * 32);
    const float w = s.x;
    tws[slot] = make_float4(w * wy0 * wx0 * yv0 * xv0,
                            w * wy0 * wx1 * yv0 * xv1,
                            w * wy1 * wx0 * yv1 * xv0,
                            w * wy1 * wx1 * yv1 * xv1);
  }
  __syncthreads();

  const int dq = t & 7, h = (t >> 3) & 7, plg = t >> 6;
  const float4 be = *(const float4*)(embed_b + l * 32 + dq * 4);
  #pragma unroll
  for (int g4 = 0; g4 < 4; ++g4) {
    const int pl = g4 * 4 + plg;
    float4 a = be;
    #pragma unroll
    for (int s = 0; s < 4; ++s) {
      const int slot = pl * 32 + h * 4 + s;
      const int4   o = tofs[slot];
      const float4 w = tws[slot];
      const float4 v00 = *(const float4*)(g + o.x + dq * 4);
      const float4 v01 = *(const float4*)(g + o.y + dq * 4);
      const float4 v10 = *(const float4*)(g + o.z + dq * 4);
      const float4 v11 = *(const float4*)(g + o.w + dq * 4);
      a.x += w.x * v00.x + w.y * v01.x + w.z * v10.x + w.w * v11.x;
      a.y += w.x * v00.y + w.y * v01.y + w.z * v10.y + w.w * v11.y;
      a.z += w.x * v00.z + w.y * v01.z + w.z * v10.z + w.w * v11.z;
      a.w += w.x * v00.w + w.y * v01.w + w.z * v10.w + w.w * v11.w;
    }
    const int gp = blk * 16 + pl;
    *(float4*)(out + (size_t)gp * 256 + h * 32 + dq * 4) = a;
  }
}

// ---------------------------------------------------------------------------
extern "C" void kernel_launch(void* const* d_in, const int* in_sizes, int n_in,
                              void* d_out, int out_size, void* d_ws, size_t ws_size,
                              hipStream_t stream) {
  const float* x      = (const float*)d_in[0];
  const float* ref    = (const float*)d_in[1];
  const float* w_attn = (const float*)d_in[6];
  const float* b_attn = (const float*)d_in[7];
  const float* w_off  = (const float*)d_in[8];
  const float* b_off  = (const float*)d_in[9];
  const float* emb_w  = (const float*)d_in[10];
  const float* emb_b  = (const float*)d_in[11];
  float* ws  = (float*)d_ws;
  float* out = (float*)d_out;

  _Float16* WuT   = (_Float16*)(ws + WU_F);
  float*    bu    = ws + BU_F;
  float*    g     = ws + G_F;
  float4*   samp4 = (float4*)(ws + SAMP_F);

  k0_unify<<<96, 256, 0, stream>>>(w_attn, b_attn, w_off, b_off, WuT, bu);

  gproj<<<dim3(85, B_), 256, 0, stream>>>(
      (const float*)d_in[2], (const float*)d_in[3],
      (const float*)d_in[4], (const float*)d_in[5], emb_w, g);

  k2_logits<<<B_ * L_ * P_ / 64, 256, 0, stream>>>(x, ref, WuT, bu, samp4);

  k3_main<<<B_ * L_ * P_ / 16, 256, 0, stream>>>(g, samp4, emb_b, out);
}

// Round 7
// 68.747 us; speedup vs baseline: 9.2892x; 1.0929x over previous
//
#include <hip/hip_runtime.h>
#include <math.h>

#define B_   8
#define L_   4
#define P_   1024
#define C_   256
#define NH_  8
#define NS_  4
#define HD_  32

typedef _Float16 half8 __attribute__((ext_vector_type(8)));
typedef float    f32x4 __attribute__((ext_vector_type(4)));

// ws layout (float offsets)
#define G_F     0u          // projected maps fp16 (l,b,s,32): 1,392,640 halves
#define SAMP_F  1392640u    // per-sample (w,fx,fy,0) float4: 32768*32*4 floats
#define WU_F    5586944u    // WuT fp16 (96,256) -> 12288 float slots
#define BU_F    5611520u    // unified bias (96)

__constant__ const int kGoff[4] = {0, 1048576, 1310720, 1376256};  // half units

// ---------------------------------------------------------------------------
// k0: build WuT fp16 (96, 256) K-major + fp32 bias bu(96)
// ---------------------------------------------------------------------------
__global__ void k0_unify(const float* __restrict__ wa, const float* __restrict__ ba,
                         const float* __restrict__ wo, const float* __restrict__ bo,
                         _Float16* __restrict__ WuT, float* __restrict__ bu) {
  const int n = blockIdx.x;    // 0..95
  const int c = threadIdx.x;   // 0..255
  const float v = (n < 32) ? wa[c * 32 + n] : wo[c * 64 + (n - 32)];
  WuT[n * 256 + c] = (_Float16)v;
  if (n == 0 && c < 96) bu[c] = (c < 32) ? ba[c] : bo[c - 32];
}

// ---------------------------------------------------------------------------
// gproj: fused transpose+project  g(b,s,:) = feat(b,:,s) @ E_l, fp16 out
// ---------------------------------------------------------------------------
__global__ __launch_bounds__(256) void gproj(
    const float* __restrict__ f0, const float* __restrict__ f1,
    const float* __restrict__ f2, const float* __restrict__ f3,
    const float* __restrict__ embed_w, _Float16* __restrict__ g16) {
  __shared__ float eL[C_ * HD_];   // 32 KB
  __shared__ float fl[32][64];     // 8 KB
  const int t = threadIdx.x;
  const int b = blockIdx.y;
  int bx = blockIdx.x, l, tile;
  const float* src;
  if (bx < 64)      { l = 0; tile = bx;      src = f0; }
  else if (bx < 80) { l = 1; tile = bx - 64; src = f1; }
  else if (bx < 84) { l = 2; tile = bx - 80; src = f2; }
  else              { l = 3; tile = 0;       src = f3; }
  const int Wl = 64 >> l, S = Wl * Wl;
  const int s0 = tile * 64;

  const float* E = embed_w + (size_t)l * (C_ * HD_);
  #pragma unroll
  for (int q = 0; q < 32; ++q) eL[q * 256 + t] = E[q * 256 + t];

  const float* sb = src + (size_t)b * C_ * S + s0;
  const int sl = t & 63, dg = t >> 6;
  float acc[8];
  #pragma unroll
  for (int e = 0; e < 8; ++e) acc[e] = 0.f;

  for (int c0 = 0; c0 < 256; c0 += 32) {
    __syncthreads();
    #pragma unroll
    for (int q = 0; q < 8; ++q) {
      const int e = q * 256 + t;
      fl[e >> 6][e & 63] = sb[(size_t)(c0 + (e >> 6)) * S + (e & 63)];
    }
    __syncthreads();
    #pragma unroll 8
    for (int ci = 0; ci < 32; ++ci) {
      const float f = fl[ci][sl];
      const float4* ep = (const float4*)&eL[(c0 + ci) * 32 + dg * 8];
      const float4 e0 = ep[0], e1 = ep[1];
      acc[0] += f * e0.x; acc[1] += f * e0.y; acc[2] += f * e0.z; acc[3] += f * e0.w;
      acc[4] += f * e1.x; acc[5] += f * e1.y; acc[6] += f * e1.z; acc[7] += f * e1.w;
    }
  }
  _Float16* gd = g16 + kGoff[l] + ((size_t)b * S + s0 + sl) * 32 + dg * 8;
  const half8 hv = {(_Float16)acc[0], (_Float16)acc[1], (_Float16)acc[2], (_Float16)acc[3],
                    (_Float16)acc[4], (_Float16)acc[5], (_Float16)acc[6], (_Float16)acc[7]};
  *(half8*)gd = hv;
}

// ---------------------------------------------------------------------------
// k2: MFMA logits GEMM (fp16 in, fp32 acc). 64 points/block (512 blocks),
// 4 waves; wave w computes pts [w*16, w*16+16) x all 96 outs.
// ---------------------------------------------------------------------------
#define XH 136          // padded half stride (272 B = 17*16 B)
#define LGS 100         // logits row stride (floats)
__global__ __launch_bounds__(256) void k2_logits(
    const float*    __restrict__ x,     // (32768, 256)
    const float*    __restrict__ ref,   // (32768, 2)
    const _Float16* __restrict__ WuT,   // (96, 256) K-major
    const float*    __restrict__ bu,    // (96)
    float4*         __restrict__ samp4) // (32768, 32)
{
  __shared__ float4 smraw4[2720];       // 43520 B, overlaid below
  _Float16* smx = (_Float16*)smraw4;            // [64][XH]
  _Float16* smw = (_Float16*)smraw4 + 64 * XH;  // [96][XH]
  float*    lg  = (float*)smraw4;               // [64][LGS] (reused after GEMM)

  const int t = threadIdx.x, blk = blockIdx.x;  // 512 blocks
  const int lane = t & 63, w = t >> 6;
  const int lr = lane & 15, kg = lane >> 4;

  f32x4 acc[6];
  #pragma unroll
  for (int nt = 0; nt < 6; ++nt) acc[nt] = (f32x4){0.f, 0.f, 0.f, 0.f};

  #pragma unroll
  for (int chunk = 0; chunk < 2; ++chunk) {
    const int c0 = chunk * 128;
    if (chunk) __syncthreads();
    {
      const int pt = t >> 2, q = t & 3;
      const float4* src = (const float4*)(x + (size_t)(blk * 64 + pt) * 256 + c0 + q * 32);
      _Float16* dst = smx + pt * XH + q * 32;
      #pragma unroll
      for (int i = 0; i < 4; ++i) {
        const float4 v0 = src[2 * i], v1 = src[2 * i + 1];
        half8 h = {(_Float16)v0.x, (_Float16)v0.y, (_Float16)v0.z, (_Float16)v0.w,
                   (_Float16)v1.x, (_Float16)v1.y, (_Float16)v1.z, (_Float16)v1.w};
        *(half8*)(dst + i * 8) = h;
      }
    }
    if (t < 192) {
      const int n = t >> 1, ho = (t & 1) * 64;
      const float4* src = (const float4*)(WuT + (size_t)n * 256 + c0 + ho);
      float4* dst = (float4*)(smw + n * XH + ho);
      #pragma unroll
      for (int i = 0; i < 8; ++i) dst[i] = src[i];
    }
    __syncthreads();

    #pragma unroll
    for (int ks = 0; ks < 4; ++ks) {
      const half8 a = *(const half8*)(smx + (w * 16 + lr) * XH + ks * 32 + kg * 8);
      #pragma unroll
      for (int nt = 0; nt < 6; ++nt) {
        const half8 bf = *(const half8*)(smw + (nt * 16 + lr) * XH + ks * 32 + kg * 8);
        acc[nt] = __builtin_amdgcn_mfma_f32_16x16x32_f16(a, bf, acc[nt], 0, 0, 0);
      }
    }
  }
  __syncthreads();

  #pragma unroll
  for (int nt = 0; nt < 6; ++nt) {
    const int n = nt * 16 + lr;
    const float bv = bu[n];
    #pragma unroll
    for (int r = 0; r < 4; ++r)
      lg[(w * 16 + kg * 4 + r) * LGS + n] = acc[nt][r] + bv;
  }
  __syncthreads();

  #pragma unroll
  for (int k = 0; k < 8; ++k) {
    const int slot = k * 256 + t;
    const int pp = slot >> 5, j = slot & 31;
    const int gp = blk * 64 + pp;
    const int l = (gp >> 10) & 3;
    const int Wl = 64 >> l;
    const float* lgp = lg + pp * LGS;
    const int h4 = (j >> 2) * 4;
    const float l0 = lgp[h4], l1 = lgp[h4 + 1], l2 = lgp[h4 + 2], l3 = lgp[h4 + 3];
    const float m = fmaxf(fmaxf(l0, l1), fmaxf(l2, l3));
    const float e0 = expf(l0 - m), e1 = expf(l1 - m), e2 = expf(l2 - m), e3 = expf(l3 - m);
    const float inv = 1.f / (e0 + e1 + e2 + e3);
    const float es[4] = {e0, e1, e2, e3};
    const float wj = es[j & 3] * inv;
    const float ox = tanhf(lgp[32 + 2 * j])     + ref[(size_t)gp * 2];
    const float oy = tanhf(lgp[32 + 2 * j + 1]) + ref[(size_t)gp * 2 + 1];
    const float sc = 0.5f * (float)(Wl - 1);
    samp4[(size_t)gp * 32 + j] = make_float4(wj, (ox + 1.f) * sc, (oy + 1.f) * sc, 0.f);
  }
}

// ---------------------------------------------------------------------------
// k3: 8 points/block (4096 blocks). Tap precompute (256 slots, 1/thread) ->
// fp16 gather: thread = (pt t>>5, head (t>>2)&7, dq t&3), 16 B half8 taps,
// fp32 accumulate, coalesced 32 B out writes.
// ---------------------------------------------------------------------------
__global__ __launch_bounds__(256) void k3_main(
    const _Float16* __restrict__ g16,
    const float4* __restrict__ samp4,
    const float* __restrict__ embed_b,   // (L, 32)
    float* __restrict__ out)             // (32768, 256)
{
  __shared__ int4   tofs[256];
  __shared__ float4 tws[256];
  const int t = threadIdx.x, blk = blockIdx.x;   // 4096 blocks
  const int gp0 = blk * 8;
  const int l = (gp0 >> 10) & 3, b = gp0 >> 12;
  const int Wl = 64 >> l;
  const int gbase = kGoff[l] + b * Wl * Wl * 32;  // half units

  {  // one tap slot per thread
    const float4 s = samp4[(size_t)gp0 * 32 + t];
    const float fx = s.y, fy = s.z;
    const float x0f = floorf(fx), y0f = floorf(fy);
    const int x0 = (int)x0f, y0 = (int)y0f, x1 = x0 + 1, y1 = y0 + 1;
    const float wx1 = fx - x0f, wy1 = fy - y0f;
    const float wx0 = 1.f - wx1, wy0 = 1.f - wy1;
    const float xv0 = (x0 >= 0 && x0 < Wl) ? 1.f : 0.f;
    const float xv1 = (x1 >= 0 && x1 < Wl) ? 1.f : 0.f;
    const float yv0 = (y0 >= 0 && y0 < Wl) ? 1.f : 0.f;
    const float yv1 = (y1 >= 0 && y1 < Wl) ? 1.f : 0.f;
    const int x0c = min(max(x0, 0), Wl - 1), x1c = min(max(x1, 0), Wl - 1);
    const int y0c = min(max(y0, 0), Wl - 1), y1c = min(max(y1, 0), Wl - 1);
    tofs[t] = make_int4(gbase + (y0c * Wl + x0c) * 32,
                        gbase + (y0c * Wl + x1c) * 32,
                        gbase + (y1c * Wl + x0c) * 32,
                        gbase + (y1c * Wl + x1c) * 32);
    const float w = s.x;
    tws[t] = make_float4(w * wy0 * wx0 * yv0 * xv0,
                         w * wy0 * wx1 * yv0 * xv1,
                         w * wy1 * wx0 * yv1 * xv0,
                         w * wy1 * wx1 * yv1 * xv1);
  }
  __syncthreads();

  const int dq = t & 3, h = (t >> 2) & 7, pt = t >> 5;
  float a[8];
  {
    const float4* bb = (const float4*)(embed_b + l * 32 + dq * 8);
    const float4 b0 = bb[0], b1 = bb[1];
    a[0] = b0.x; a[1] = b0.y; a[2] = b0.z; a[3] = b0.w;
    a[4] = b1.x; a[5] = b1.y; a[6] = b1.z; a[7] = b1.w;
  }
  #pragma unroll
  for (int s = 0; s < 4; ++s) {
    const int slot = pt * 32 + h * 4 + s;
    const int4   o = tofs[slot];
    const float4 w = tws[slot];
    const half8 v00 = *(const half8*)(g16 + o.x + dq * 8);
    const half8 v01 = *(const half8*)(g16 + o.y + dq * 8);
    const half8 v10 = *(const half8*)(g16 + o.z + dq * 8);
    const half8 v11 = *(const half8*)(g16 + o.w + dq * 8);
    #pragma unroll
    for (int j = 0; j < 8; ++j)
      a[j] += w.x * (float)v00[j] + w.y * (float)v01[j]
            + w.z * (float)v10[j] + w.w * (float)v11[j];
  }
  float* od = out + (size_t)(gp0 + pt) * 256 + h * 32 + dq * 8;
  ((float4*)od)[0] = make_float4(a[0], a[1], a[2], a[3]);
  ((float4*)od)[1] = make_float4(a[4], a[5], a[6], a[7]);
}

// ---------------------------------------------------------------------------
extern "C" void kernel_launch(void* const* d_in, const int* in_sizes, int n_in,
                              void* d_out, int out_size, void* d_ws, size_t ws_size,
                              hipStream_t stream) {
  const float* x      = (const float*)d_in[0];
  const float* ref    = (const float*)d_in[1];
  const float* w_attn = (const float*)d_in[6];
  const float* b_attn = (const float*)d_in[7];
  const float* w_off  = (const float*)d_in[8];
  const float* b_off  = (const float*)d_in[9];
  const float* emb_w  = (const float*)d_in[10];
  const float* emb_b  = (const float*)d_in[11];
  float* ws  = (float*)d_ws;
  float* out = (float*)d_out;

  _Float16* WuT   = (_Float16*)(ws + WU_F);
  float*    bu    = ws + BU_F;
  _Float16* g16   = (_Float16*)(ws + G_F);
  float4*   samp4 = (float4*)(ws + SAMP_F);

  k0_unify<<<96, 256, 0, stream>>>(w_attn, b_attn, w_off, b_off, WuT, bu);

  gproj<<<dim3(85, B_), 256, 0, stream>>>(
      (const float*)d_in[2], (const float*)d_in[3],
      (const float*)d_in[4], (const float*)d_in[5], emb_w, g16);

  k2_logits<<<B_ * L_ * P_ / 64, 256, 0, stream>>>(x, ref, WuT, bu, samp4);

  k3_main<<<B_ * L_ * P_ / 8, 256, 0, stream>>>(g16, samp4, emb_b, out);
}